// Round 1
// baseline (402.590 us; speedup 1.0000x reference)
//
#include <hip/hip_runtime.h>

// Problem constants
#define B_    32
#define CIN_  256
#define H_    64
#define W_    64
#define KSZ   9
#define STR   2
#define OH_   28
#define OW_   28
#define COUT_ 256          // 32 caps * 8 os0 * 1 os1
#define M_TOTAL 25088      // B*OH*OW
#define POSE_ELEMS 6422528 // B*32*OH*OW*8

typedef _Float16 f16;
typedef _Float16 f16x8 __attribute__((ext_vector_type(8)));
typedef _Float16 f16x4 __attribute__((ext_vector_type(4)));
typedef float    f32x4 __attribute__((ext_vector_type(4)));

// async global->LDS, 16B per lane; LDS dest is wave-uniform base + lane*16
#define GLD_LDS16(gp, lp) __builtin_amdgcn_global_load_lds( \
    (const __attribute__((address_space(1))) void*)(gp),    \
    (__attribute__((address_space(3))) void*)(lp), 16, 0, 0)

// ---------------------------------------------------------------------------
// Kernel 1: x [B,CIN,H,W] fp32 (NCHW) -> Xt [B,H,W,CIN] fp16 (NHWC)
// Block: (cblk, h, b); transposes a [64 cin][64 w] tile through LDS.
// ---------------------------------------------------------------------------
__global__ __launch_bounds__(256) void xt_kernel(const float* __restrict__ x,
                                                 f16* __restrict__ Xt)
{
    __shared__ float tile[64 * 65];
    const int t    = threadIdx.x;
    const int c0   = blockIdx.x * 64;   // 0..3 -> cin block
    const int h    = blockIdx.y;        // 0..63
    const int b    = blockIdx.z;        // 0..31

    const float* src = x + (((long)(b * CIN_ + c0)) * H_ + h) * W_;
    const int ci = t >> 6, w = t & 63;
#pragma unroll
    for (int it = 0; it < 16; ++it) {
        const int c = it * 4 + ci;
        tile[c * 65 + w] = src[(long)c * (H_ * W_) + w];
    }
    __syncthreads();

    f16* dst = Xt + ((long)(b * H_ + h) * W_) * CIN_ + c0;
    const int wq = t >> 4, cq = t & 15;
#pragma unroll
    for (int it = 0; it < 4; ++it) {
        const int w2 = it * 16 + wq;
        f16x4 v;
        v[0] = (f16)tile[(cq * 4 + 0) * 65 + w2];
        v[1] = (f16)tile[(cq * 4 + 1) * 65 + w2];
        v[2] = (f16)tile[(cq * 4 + 2) * 65 + w2];
        v[3] = (f16)tile[(cq * 4 + 3) * 65 + w2];
        *(f16x4*)(dst + (long)w2 * CIN_ + cq * 4) = v;
    }
}

// ---------------------------------------------------------------------------
// Kernel 2: conv_w [COUT,CIN,9,9] fp32 -> Wt [kh*9+kw][COUT][CIN] fp16
// Block: (co, cin-block of 64). Coalesced read, 128B-contiguous writes.
// ---------------------------------------------------------------------------
__global__ __launch_bounds__(256) void wt_kernel(const float* __restrict__ w,
                                                 f16* __restrict__ Wt)
{
    __shared__ float tile[64 * 81];
    const int t  = threadIdx.x;
    const int co = blockIdx.x >> 2;
    const int c0 = (blockIdx.x & 3) * 64;
    const float* src = w + ((long)co * CIN_ + c0) * 81;
    for (int i = t; i < 64 * 81; i += 256) tile[i] = src[i];
    __syncthreads();
    for (int i = t; i < 64 * 81; i += 256) {
        const int khw = i >> 6, ci = i & 63;
        Wt[(long)khw * (COUT_ * CIN_) + co * CIN_ + c0 + ci] = (f16)tile[ci * 81 + khw];
    }
}

// ---------------------------------------------------------------------------
// Kernel 3: implicit-GEMM conv. C[m][n] = sum_{kh,kw,cin} Xt[b,2oh+kh,2ow+kw,cin] * Wt[khw][n][cin]
// 128x128 tile, BK=64, 4 waves (each 64x64 = 4x4 frags of 16x16), mfma 16x16x32 f16.
// LDS tiles XOR-swizzled (T2): byte_in_row ^= (row&7)<<4; staged via
// global_load_lds with pre-swizzled global source (linear LDS dest).
// ---------------------------------------------------------------------------
__global__ __launch_bounds__(256, 2) void gemm_kernel(const f16* __restrict__ Xt,
                                                      const f16* __restrict__ Wt,
                                                      const float* __restrict__ bias,
                                                      float* __restrict__ caps)
{
    __shared__ __align__(16) char lds[32768];   // A: [0,16K), B: [16K,32K)
    const int t    = threadIdx.x;
    const int lane = t & 63, wave = t >> 6;
    const int mt = blockIdx.x >> 1, nt = blockIdx.x & 1;  // 196 x 2
    const int m0 = mt * 128, n0 = nt * 128;

    // ---- staging source bases (per-thread, K-step-invariant) ----
    // issue j = wave*4+i writes LDS bytes [j*1024, j*1024+1024) = rows r=j*8..j*8+7
    // lane's row r = j*8 + (lane>>3); linear chunk (lane&7) holds global chunk (lane&7)^(r&7)
    const int csrc = ((lane & 7) ^ (lane >> 3)) * 8;  // fp16 elems
    int aoff[4], boff[4];
#pragma unroll
    for (int i = 0; i < 4; ++i) {
        const int j = wave * 4 + i;
        const int r = j * 8 + (lane >> 3);
        const int m = m0 + r;
        const int b   = m / 784;
        const int rem = m - b * 784;
        const int oh  = rem / 28;
        const int ow  = rem - oh * 28;
        aoff[i] = ((b * 64 + 2 * oh) * 64 + 2 * ow) * 256 + csrc;
        boff[i] = (n0 + r) * 256 + csrc;
    }

    // ---- fragment-read lane addressing ----
    const int wm = wave >> 1, wn = wave & 1;  // 2x2 wave grid, 64x64 each
    const int lane_sw = ((lane >> 4) * 16) ^ ((lane & 7) << 4); // swizzled byte-in-row (k part)
    const char* aptr = lds + wm * 8192 + (lane & 15) * 128;
    const char* bptr = lds + 16384 + wn * 8192 + (lane & 15) * 128;

    f32x4 acc[4][4];
    const f32x4 z = {0.f, 0.f, 0.f, 0.f};
#pragma unroll
    for (int i = 0; i < 4; ++i)
#pragma unroll
        for (int j = 0; j < 4; ++j) acc[i][j] = z;

#pragma unroll 1
    for (int ks = 0; ks < 324; ++ks) {           // (kh*9+kw)*4 + cb
        const int cb  = ks & 3;
        const int khw = ks >> 2;
        const int kh  = khw / 9;
        const int kw  = khw - kh * 9;
        const int akoff = (kh * 64 + kw) * 256 + cb * 64;
        const int bkoff = khw * 65536 + cb * 64;

        __syncthreads();  // previous tile fully consumed
#pragma unroll
        for (int i = 0; i < 4; ++i)
            GLD_LDS16(Xt + aoff[i] + akoff, lds + (wave * 4 + i) * 1024);
#pragma unroll
        for (int i = 0; i < 4; ++i)
            GLD_LDS16(Wt + boff[i] + bkoff, lds + 16384 + (wave * 4 + i) * 1024);
        __syncthreads();  // compiler drains vmcnt before s_barrier

        f16x8 af[4][2], bf[4][2];
#pragma unroll
        for (int am = 0; am < 4; ++am) {
            af[am][0] = *(const f16x8*)(aptr + am * 2048 + (0 ^ lane_sw));
            af[am][1] = *(const f16x8*)(aptr + am * 2048 + (64 ^ lane_sw));
        }
#pragma unroll
        for (int bn = 0; bn < 4; ++bn) {
            bf[bn][0] = *(const f16x8*)(bptr + bn * 2048 + (0 ^ lane_sw));
            bf[bn][1] = *(const f16x8*)(bptr + bn * 2048 + (64 ^ lane_sw));
        }
#pragma unroll
        for (int am = 0; am < 4; ++am)
#pragma unroll
            for (int bn = 0; bn < 4; ++bn) {
                acc[am][bn] = __builtin_amdgcn_mfma_f32_16x16x32_f16(af[am][0], bf[bn][0], acc[am][bn], 0, 0, 0);
                acc[am][bn] = __builtin_amdgcn_mfma_f32_16x16x32_f16(af[am][1], bf[bn][1], acc[am][bn], 0, 0, 0);
            }
    }

    // ---- epilogue: C/D layout col=lane&15 (n), row=(lane>>4)*4+j (m) ----
    const int lrow = (lane >> 4) * 4;
#pragma unroll
    for (int bn = 0; bn < 4; ++bn) {
        const int n = n0 + wn * 64 + bn * 16 + (lane & 15);
        const float bv = bias[n];
#pragma unroll
        for (int am = 0; am < 4; ++am) {
            const long mrow = m0 + wm * 64 + am * 16 + lrow;
            float* cw = caps + mrow * 256 + n;
#pragma unroll
            for (int j = 0; j < 4; ++j) cw[(long)j * 256] = acc[am][bn][j] + bv;
        }
    }
}

// ---------------------------------------------------------------------------
// Kernel 4: squash + 3-iter dynamic routing + acts.
// 32 lanes = 32 capsule types for one position m=(b,oh,ow); softmax over the
// 32-lane group via __shfl_xor(width=32). 8 positions per 256-thread block.
// ---------------------------------------------------------------------------
__global__ __launch_bounds__(256) void routing_kernel(const float* __restrict__ caps,
                                                      const float* __restrict__ rb,
                                                      float* __restrict__ out)
{
    const int t   = threadIdx.x;
    const int m   = blockIdx.x * 8 + (t >> 5);
    const int cap = t & 31;
    const int b   = m / 784;
    const int rem = m - b * 784;
    const int oh  = rem / 28;
    const int ow  = rem - oh * 28;

    const float4* cp = (const float4*)(caps + (long)m * 256 + cap * 8);
    const float4 u0 = cp[0], u1 = cp[1];
    float v[8] = {u0.x, u0.y, u0.z, u0.w, u1.x, u1.y, u1.z, u1.w};

    float n2 = 0.f;
#pragma unroll
    for (int j = 0; j < 8; ++j) n2 += v[j] * v[j];
    const float f = (n2 / (1.f + n2)) / sqrtf(n2 + 1e-8f);
    float votes[8];
#pragma unroll
    for (int j = 0; j < 8; ++j) votes[j] = f * v[j];

    const float4* rp = (const float4*)(rb + ((long)(cap * 28 + oh) * 28 + ow) * 8);
    const float4 r0 = rp[0], r1 = rp[1];
    const float rbv[8] = {r0.x, r0.y, r0.z, r0.w, r1.x, r1.y, r1.z, r1.w};

    float logit = 0.f;
    float poses[8];
#pragma unroll 1
    for (int it = 0; it < 3; ++it) {
        float mx = logit;
#pragma unroll
        for (int d = 16; d > 0; d >>= 1) mx = fmaxf(mx, __shfl_xor(mx, d, 32));
        const float e = __expf(logit - mx);
        float se = e;
#pragma unroll
        for (int d = 16; d > 0; d >>= 1) se += __shfl_xor(se, d, 32);
        const float c = e / se;

        float s[8];
        float sn2 = 0.f;
#pragma unroll
        for (int j = 0; j < 8; ++j) { s[j] = c * votes[j] + rbv[j]; sn2 += s[j] * s[j]; }
        const float sf = (sn2 / (1.f + sn2)) / sqrtf(sn2 + 1e-8f);
        float dot = 0.f;
#pragma unroll
        for (int j = 0; j < 8; ++j) { poses[j] = sf * s[j]; dot += votes[j] * poses[j]; }
        logit += dot;
    }

    float pn2 = 0.f;
#pragma unroll
    for (int j = 0; j < 8; ++j) pn2 += poses[j] * poses[j];
    const float act = sqrtf(pn2);

    float* po = out + (((long)(b * 32 + cap) * 28 + oh) * 28 + ow) * 8;
    float4 o0 = {poses[0], poses[1], poses[2], poses[3]};
    float4 o1 = {poses[4], poses[5], poses[6], poses[7]};
    ((float4*)po)[0] = o0;
    ((float4*)po)[1] = o1;
    out[POSE_ELEMS + ((long)(b * 32 + cap) * 28 + oh) * 28 + ow] = act;
}

// ---------------------------------------------------------------------------
extern "C" void kernel_launch(void* const* d_in, const int* in_sizes, int n_in,
                              void* d_out, int out_size, void* d_ws, size_t ws_size,
                              hipStream_t stream)
{
    const float* x      = (const float*)d_in[0];
    const float* conv_w = (const float*)d_in[1];
    const float* conv_b = (const float*)d_in[2];
    const float* rb     = (const float*)d_in[3];
    float* out          = (float*)d_out;

    char* ws = (char*)d_ws;
    f16*   Xt   = (f16*)ws;                                  // 67,108,864 B
    f16*   Wt   = (f16*)(ws + 67108864);                     // 10,616,832 B
    float* caps = (float*)(ws + 67108864 + 10616832);        // 25,690,112 B

    xt_kernel<<<dim3(4, 64, 32), 256, 0, stream>>>(x, Xt);
    wt_kernel<<<dim3(1024), 256, 0, stream>>>(conv_w, Wt);
    gemm_kernel<<<dim3(392), 256, 0, stream>>>(Xt, Wt, conv_b, caps);
    routing_kernel<<<dim3(3136), 256, 0, stream>>>(caps, rb, out);
}

// Round 2
// 400.228 us; speedup vs baseline: 1.0059x; 1.0059x over previous
//
#include <hip/hip_runtime.h>

// Problem constants
#define B_    32
#define CIN_  256
#define H_    64
#define W_    64
#define KSZ   9
#define STR   2
#define OH_   28
#define OW_   28
#define COUT_ 256          // 32 caps * 8 os0 * 1 os1
#define M_TOTAL 25088      // B*OH*OW
#define POSE_ELEMS 6422528 // B*32*OH*OW*8

typedef _Float16 f16;
typedef _Float16 f16x8 __attribute__((ext_vector_type(8)));
typedef _Float16 f16x4 __attribute__((ext_vector_type(4)));
typedef float    f32x4 __attribute__((ext_vector_type(4)));

// async global->LDS, 16B per lane; LDS dest is wave-uniform base + lane*16
#define GLD_LDS16(gp, lp) __builtin_amdgcn_global_load_lds( \
    (const __attribute__((address_space(1))) void*)(gp),    \
    (__attribute__((address_space(3))) void*)(lp), 16, 0, 0)

// ---------------------------------------------------------------------------
// Kernel 1: x [B,CIN,H,W] fp32 (NCHW) -> Xt [B,H,W,CIN] fp16 (NHWC)
// ---------------------------------------------------------------------------
__global__ __launch_bounds__(256) void xt_kernel(const float* __restrict__ x,
                                                 f16* __restrict__ Xt)
{
    __shared__ float tile[64 * 65];
    const int t    = threadIdx.x;
    const int c0   = blockIdx.x * 64;   // 0..3 -> cin block
    const int h    = blockIdx.y;        // 0..63
    const int b    = blockIdx.z;        // 0..31

    const float* src = x + (((long)(b * CIN_ + c0)) * H_ + h) * W_;
    const int ci = t >> 6, w = t & 63;
#pragma unroll
    for (int it = 0; it < 16; ++it) {
        const int c = it * 4 + ci;
        tile[c * 65 + w] = src[(long)c * (H_ * W_) + w];
    }
    __syncthreads();

    f16* dst = Xt + ((long)(b * H_ + h) * W_) * CIN_ + c0;
    const int wq = t >> 4, cq = t & 15;
#pragma unroll
    for (int it = 0; it < 4; ++it) {
        const int w2 = it * 16 + wq;
        f16x4 v;
        v[0] = (f16)tile[(cq * 4 + 0) * 65 + w2];
        v[1] = (f16)tile[(cq * 4 + 1) * 65 + w2];
        v[2] = (f16)tile[(cq * 4 + 2) * 65 + w2];
        v[3] = (f16)tile[(cq * 4 + 3) * 65 + w2];
        *(f16x4*)(dst + (long)w2 * CIN_ + cq * 4) = v;
    }
}

// ---------------------------------------------------------------------------
// Kernel 2: conv_w [COUT,CIN,9,9] fp32 -> Wt [kh*9+kw][COUT][CIN] fp16
// ---------------------------------------------------------------------------
__global__ __launch_bounds__(256) void wt_kernel(const float* __restrict__ w,
                                                 f16* __restrict__ Wt)
{
    __shared__ float tile[64 * 81];
    const int t  = threadIdx.x;
    const int co = blockIdx.x >> 2;
    const int c0 = (blockIdx.x & 3) * 64;
    const float* src = w + ((long)co * CIN_ + c0) * 81;
    for (int i = t; i < 64 * 81; i += 256) tile[i] = src[i];
    __syncthreads();
    for (int i = t; i < 64 * 81; i += 256) {
        const int khw = i >> 6, ci = i & 63;
        Wt[(long)khw * (COUT_ * CIN_) + co * CIN_ + c0 + ci] = (f16)tile[ci * 81 + khw];
    }
}

// ---------------------------------------------------------------------------
// Kernel 3: split-K implicit-GEMM conv.
// grid = 392*nsplit blocks; each block: 128x128 output tile, K-steps
// [sk*ksteps, (sk+1)*ksteps) of 324, writes fp32 partial slice sk.
// XCD swizzle: each XCD owns one contiguous (sk,nt) stripe of 196 mt-tiles
// (Wt slice ~5.3MB stays L2-warm per XCD).
// ---------------------------------------------------------------------------
__global__ __launch_bounds__(256, 4) void gemm_kernel(const f16* __restrict__ Xt,
                                                      const f16* __restrict__ Wt,
                                                      float* __restrict__ part,
                                                      int nsplit, int ksteps)
{
    __shared__ __align__(16) char lds[32768];   // A: [0,16K), B: [16K,32K)
    const int t    = threadIdx.x;
    const int lane = t & 63, wave = t >> 6;

    // XCD-aware swizzle over linear grid (total = 392*nsplit, divisible by 8)
    const int bid   = blockIdx.x;
    const int chunk = 49 * nsplit;
    const int l2id  = (bid & 7) * chunk + (bid >> 3);
    const int sk = l2id / 392;
    const int r  = l2id - sk * 392;
    const int nt = r / 196;
    const int mt = r - nt * 196;
    const int m0 = mt * 128, n0 = nt * 128;

    // ---- staging source bases (per-thread, K-step-invariant) ----
    // issue j = wave*4+i writes LDS bytes [j*1024, j*1024+1024) = rows r=j*8..j*8+7
    // lane's row r = j*8 + (lane>>3); linear chunk (lane&7) holds global chunk (lane&7)^(r&7)
    const int csrc = ((lane & 7) ^ (lane >> 3)) * 8;  // fp16 elems
    int aoff[4], boff[4];
#pragma unroll
    for (int i = 0; i < 4; ++i) {
        const int j = wave * 4 + i;
        const int rr = j * 8 + (lane >> 3);
        const int m = m0 + rr;
        const int b   = m / 784;
        const int rem = m - b * 784;
        const int oh  = rem / 28;
        const int ow  = rem - oh * 28;
        aoff[i] = ((b * 64 + 2 * oh) * 64 + 2 * ow) * 256 + csrc;
        boff[i] = (n0 + rr) * 256 + csrc;
    }

    // ---- fragment-read lane addressing ----
    const int wm = wave >> 1, wn = wave & 1;  // 2x2 wave grid, 64x64 each
    const int lane_sw = ((lane >> 4) * 16) ^ ((lane & 7) << 4); // swizzled byte-in-row (k part)
    const char* aptr = lds + wm * 8192 + (lane & 15) * 128;
    const char* bptr = lds + 16384 + wn * 8192 + (lane & 15) * 128;

    f32x4 acc[4][4];
    const f32x4 z = {0.f, 0.f, 0.f, 0.f};
#pragma unroll
    for (int i = 0; i < 4; ++i)
#pragma unroll
        for (int j = 0; j < 4; ++j) acc[i][j] = z;

    const int ksb = sk * ksteps;
#pragma unroll 1
    for (int ks = ksb; ks < ksb + ksteps; ++ks) {    // ks = khw*4 + cb
        const int cb  = ks & 3;
        const int khw = ks >> 2;
        const int kh  = khw / 9;
        const int kw  = khw - kh * 9;
        const int akoff = (kh * 64 + kw) * 256 + cb * 64;
        const int bkoff = khw * 65536 + cb * 64;

        __syncthreads();  // previous tile fully consumed
#pragma unroll
        for (int i = 0; i < 4; ++i)
            GLD_LDS16(Xt + aoff[i] + akoff, lds + (wave * 4 + i) * 1024);
#pragma unroll
        for (int i = 0; i < 4; ++i)
            GLD_LDS16(Wt + boff[i] + bkoff, lds + 16384 + (wave * 4 + i) * 1024);
        __syncthreads();  // compiler drains vmcnt before s_barrier

        f16x8 af[4][2], bf[4][2];
#pragma unroll
        for (int am = 0; am < 4; ++am) {
            af[am][0] = *(const f16x8*)(aptr + am * 2048 + (0 ^ lane_sw));
            af[am][1] = *(const f16x8*)(aptr + am * 2048 + (64 ^ lane_sw));
        }
#pragma unroll
        for (int bn = 0; bn < 4; ++bn) {
            bf[bn][0] = *(const f16x8*)(bptr + bn * 2048 + (0 ^ lane_sw));
            bf[bn][1] = *(const f16x8*)(bptr + bn * 2048 + (64 ^ lane_sw));
        }
#pragma unroll
        for (int am = 0; am < 4; ++am)
#pragma unroll
            for (int bn = 0; bn < 4; ++bn) {
                acc[am][bn] = __builtin_amdgcn_mfma_f32_16x16x32_f16(af[am][0], bf[bn][0], acc[am][bn], 0, 0, 0);
                acc[am][bn] = __builtin_amdgcn_mfma_f32_16x16x32_f16(af[am][1], bf[bn][1], acc[am][bn], 0, 0, 0);
            }
    }

    // ---- epilogue: C/D layout col=lane&15 (n), row=(lane>>4)*4+j (m) ----
    float* base = part + (long)sk * (M_TOTAL * 256);
    const int lrow = (lane >> 4) * 4;
#pragma unroll
    for (int bn = 0; bn < 4; ++bn) {
        const int n = n0 + wn * 64 + bn * 16 + (lane & 15);
#pragma unroll
        for (int am = 0; am < 4; ++am) {
            const long mrow = m0 + wm * 64 + am * 16 + lrow;
            float* cw = base + mrow * 256 + n;
#pragma unroll
            for (int j = 0; j < 4; ++j) cw[(long)j * 256] = acc[am][bn][j];
        }
    }
}

// ---------------------------------------------------------------------------
// Kernel 4: partial-sum + bias + squash + 3-iter routing + acts.
// 32 lanes = 32 capsule types for one position m=(b,oh,ow).
// ---------------------------------------------------------------------------
__global__ __launch_bounds__(256) void routing_kernel(const float* __restrict__ part,
                                                      const float* __restrict__ bias,
                                                      const float* __restrict__ rb,
                                                      float* __restrict__ out, int nsplit)
{
    const int t   = threadIdx.x;
    const int m   = blockIdx.x * 8 + (t >> 5);
    const int cap = t & 31;
    const int b   = m / 784;
    const int rem = m - b * 784;
    const int oh  = rem / 28;
    const int ow  = rem - oh * 28;

    const float4 b0 = ((const float4*)(bias + cap * 8))[0];
    const float4 b1 = ((const float4*)(bias + cap * 8))[1];
    float v[8] = {b0.x, b0.y, b0.z, b0.w, b1.x, b1.y, b1.z, b1.w};
#pragma unroll 1
    for (int sk = 0; sk < nsplit; ++sk) {
        const float4* cp = (const float4*)(part + (long)sk * (M_TOTAL * 256) + (long)m * 256 + cap * 8);
        const float4 u0 = cp[0], u1 = cp[1];
        v[0] += u0.x; v[1] += u0.y; v[2] += u0.z; v[3] += u0.w;
        v[4] += u1.x; v[5] += u1.y; v[6] += u1.z; v[7] += u1.w;
    }

    float n2 = 0.f;
#pragma unroll
    for (int j = 0; j < 8; ++j) n2 += v[j] * v[j];
    const float f = (n2 / (1.f + n2)) / sqrtf(n2 + 1e-8f);
    float votes[8];
#pragma unroll
    for (int j = 0; j < 8; ++j) votes[j] = f * v[j];

    const float4* rp = (const float4*)(rb + ((long)(cap * 28 + oh) * 28 + ow) * 8);
    const float4 r0 = rp[0], r1 = rp[1];
    const float rbv[8] = {r0.x, r0.y, r0.z, r0.w, r1.x, r1.y, r1.z, r1.w};

    float logit = 0.f;
    float poses[8];
#pragma unroll 1
    for (int it = 0; it < 3; ++it) {
        float mx = logit;
#pragma unroll
        for (int d = 16; d > 0; d >>= 1) mx = fmaxf(mx, __shfl_xor(mx, d, 32));
        const float e = __expf(logit - mx);
        float se = e;
#pragma unroll
        for (int d = 16; d > 0; d >>= 1) se += __shfl_xor(se, d, 32);
        const float c = e / se;

        float s[8];
        float sn2 = 0.f;
#pragma unroll
        for (int j = 0; j < 8; ++j) { s[j] = c * votes[j] + rbv[j]; sn2 += s[j] * s[j]; }
        const float sf = (sn2 / (1.f + sn2)) / sqrtf(sn2 + 1e-8f);
        float dot = 0.f;
#pragma unroll
        for (int j = 0; j < 8; ++j) { poses[j] = sf * s[j]; dot += votes[j] * poses[j]; }
        logit += dot;
    }

    float pn2 = 0.f;
#pragma unroll
    for (int j = 0; j < 8; ++j) pn2 += poses[j] * poses[j];
    const float act = sqrtf(pn2);

    float* po = out + (((long)(b * 32 + cap) * 28 + oh) * 28 + ow) * 8;
    float4 o0 = {poses[0], poses[1], poses[2], poses[3]};
    float4 o1 = {poses[4], poses[5], poses[6], poses[7]};
    ((float4*)po)[0] = o0;
    ((float4*)po)[1] = o1;
    out[POSE_ELEMS + ((long)(b * 32 + cap) * 28 + oh) * 28 + ow] = act;
}

// ---------------------------------------------------------------------------
extern "C" void kernel_launch(void* const* d_in, const int* in_sizes, int n_in,
                              void* d_out, int out_size, void* d_ws, size_t ws_size,
                              hipStream_t stream)
{
    const float* x      = (const float*)d_in[0];
    const float* conv_w = (const float*)d_in[1];
    const float* conv_b = (const float*)d_in[2];
    const float* rb     = (const float*)d_in[3];
    float* out          = (float*)d_out;

    char* ws = (char*)d_ws;
    f16*   Xt   = (f16*)ws;                                  // 67,108,864 B
    f16*   Wt   = (f16*)(ws + 67108864);                     // 10,616,832 B
    const size_t base = 67108864 + 10616832;                 // 77,725,696 B
    float* part = (float*)(ws + base);
    const size_t part_bytes = (size_t)M_TOTAL * 256 * 4;     // 25,690,112 B

    // split-K factor limited by workspace (deterministic: ws_size is fixed)
    int nsplit = 1;
    if      (ws_size >= base + 4 * part_bytes) nsplit = 4;
    else if (ws_size >= base + 2 * part_bytes) nsplit = 2;
    const int ksteps = 324 / nsplit;

    xt_kernel<<<dim3(4, 64, 32), 256, 0, stream>>>(x, Xt);
    wt_kernel<<<dim3(1024), 256, 0, stream>>>(conv_w, Wt);
    gemm_kernel<<<dim3(392 * nsplit), 256, 0, stream>>>(Xt, Wt, part, nsplit, ksteps);
    routing_kernel<<<dim3(3136), 256, 0, stream>>>(part, conv_b, rb, out, nsplit);
}

// Round 3
// 374.472 us; speedup vs baseline: 1.0751x; 1.0688x over previous
//
#include <hip/hip_runtime.h>

// Problem constants
#define B_    32
#define CIN_  256
#define H_    64
#define W_    64
#define OH_   28
#define OW_   28
#define M_TOTAL 25088      // B*OH*OW
#define POSE_ELEMS 6422528 // B*32*OH*OW*8

typedef _Float16 f16;
typedef _Float16 f16x8 __attribute__((ext_vector_type(8)));
typedef _Float16 f16x4 __attribute__((ext_vector_type(4)));
typedef float    f32x4 __attribute__((ext_vector_type(4)));

#define GLD_LDS16(gp, lp) __builtin_amdgcn_global_load_lds( \
    (const __attribute__((address_space(1))) void*)(gp),    \
    (__attribute__((address_space(3))) void*)(lp), 16, 0, 0)

#define SBAR()   asm volatile("s_barrier" ::: "memory")
#define WAITVM2() asm volatile("s_waitcnt vmcnt(2)" ::: "memory")
#define WAITVM4() asm volatile("s_waitcnt vmcnt(4)" ::: "memory")

// ---------------------------------------------------------------------------
// Kernel 1: x [B,CIN,H,W] fp32 -> Xt [B,H,W,CIN] fp16
// ---------------------------------------------------------------------------
__global__ __launch_bounds__(256) void xt_kernel(const float* __restrict__ x,
                                                 f16* __restrict__ Xt)
{
    __shared__ float tile[64 * 65];
    const int t  = threadIdx.x;
    const int c0 = blockIdx.x * 64;
    const int h  = blockIdx.y;
    const int b  = blockIdx.z;

    const float* src = x + (((long)(b * CIN_ + c0)) * H_ + h) * W_;
    const int ci = t >> 6, w = t & 63;
#pragma unroll
    for (int it = 0; it < 16; ++it) {
        const int c = it * 4 + ci;
        tile[c * 65 + w] = src[(long)c * (H_ * W_) + w];
    }
    __syncthreads();

    f16* dst = Xt + ((long)(b * H_ + h) * W_) * CIN_ + c0;
    const int wq = t >> 4, cq = t & 15;
#pragma unroll
    for (int it = 0; it < 4; ++it) {
        const int w2 = it * 16 + wq;
        f16x4 v;
        v[0] = (f16)tile[(cq * 4 + 0) * 65 + w2];
        v[1] = (f16)tile[(cq * 4 + 1) * 65 + w2];
        v[2] = (f16)tile[(cq * 4 + 2) * 65 + w2];
        v[3] = (f16)tile[(cq * 4 + 3) * 65 + w2];
        *(f16x4*)(dst + (long)w2 * CIN_ + cq * 4) = v;
    }
}

// ---------------------------------------------------------------------------
// Kernel 2: conv_w [COUT,CIN,9,9] fp32 -> Wt [khw][COUT][CIN] fp16
// ---------------------------------------------------------------------------
__global__ __launch_bounds__(256) void wt_kernel(const float* __restrict__ w,
                                                 f16* __restrict__ Wt)
{
    __shared__ float tile[64 * 81];
    const int t  = threadIdx.x;
    const int co = blockIdx.x >> 2;
    const int c0 = (blockIdx.x & 3) * 64;
    const float* src = w + ((long)co * 256 + c0) * 81;
    for (int i = t; i < 64 * 81; i += 256) tile[i] = src[i];
    __syncthreads();
    for (int i = t; i < 64 * 81; i += 256) {
        const int khw = i >> 6, ci = i & 63;
        Wt[(long)khw * 65536 + co * 256 + c0 + ci] = (f16)tile[ci * 81 + khw];
    }
}

// ---------------------------------------------------------------------------
// Kernel 3: 8-phase split-K implicit-GEMM (256x256 tile, BK=64, 8 waves).
// A-half0 = mf0-3 rows of both wave-rows (perm), B-half0 = nf0-1 rows of all
// wave-cols. Per K-tile: 4 phases {stage half(t+1), ds_read subtile, s_barrier,
// setprio+16 MFMA, s_barrier}, counted vmcnt(2)/vmcnt(4), raw barriers.
// ---------------------------------------------------------------------------
__global__ __launch_bounds__(512, 2) void gemm_kernel(const f16* __restrict__ Xt,
                                                      const f16* __restrict__ Wt,
                                                      float* __restrict__ part,
                                                      int nsplit, int NT)
{
    __shared__ __align__(16) char lds[131072]; // A: 2x32K at 0, B: 2x32K at 64K
    char* ldsA = lds;
    char* ldsB = lds + 65536;

    const int t    = threadIdx.x;
    const int lane = t & 63, wave = t >> 6;

    // bijective XCD swizzle (m204)
    const int nwg = 98 * nsplit;
    const int q = nwg >> 3, r8 = nwg & 7;
    const int xcd = blockIdx.x & 7, idx = blockIdx.x >> 3;
    const int wgid = (xcd < r8 ? xcd * (q + 1) : r8 * (q + 1) + (xcd - r8) * q) + idx;
    const int sk = wgid / 98;
    const int mt = wgid - sk * 98;
    const int m0 = mt * 256;
    const int ksb = sk * NT;

    // ---- staging source offsets (slot j = i*8+wave, rows j*8+(lane>>3)) ----
    const int csrc = ((lane & 7) ^ (lane >> 3)) * 8;
    int aoff[4], boff[4];
#pragma unroll
    for (int i = 0; i < 4; ++i) {
        const int r  = (i * 8 + wave) * 8 + (lane >> 3);
        const int ga = (r & 63) + ((r >> 6) & 1) * 128 + (r >> 7) * 64;  // permA
        const int m  = m0 + ga;
        const int b   = m / 784;
        const int rem = m - b * 784;
        const int oh  = rem / 28;
        const int ow  = rem - oh * 28;
        aoff[i] = ((b * 64 + 2 * oh) * 64 + 2 * ow) * 256 + csrc;
        const int gb = (r & 31) + ((r >> 5) & 3) * 64 + (r >> 7) * 32;   // permB fwd
        boff[i] = gb * 256 + csrc;
    }

    // ---- fragment-read addressing ----
    const int wm = wave >> 2, wn = wave & 3;   // 2x4 wave grid, 128x64 each
    int rowA[8], rowB[4];
#pragma unroll
    for (int mf = 0; mf < 8; ++mf) {
        const int g  = wm * 128 + mf * 16 + (lane & 15);
        const int lr = (g & 63) + ((g >> 6) & 1) * 128 + (g >> 7) * 64;  // permA (involution)
        rowA[mf] = lr * 128;
    }
#pragma unroll
    for (int nf = 0; nf < 4; ++nf) {
        const int g  = wn * 64 + nf * 16 + (lane & 15);
        const int lr = (g & 31) + ((g >> 6) << 5) + ((g >> 5) & 1) * 128; // permB inv
        rowB[nf] = lr * 128;
    }
    int csw[2];
    csw[0] = ((lane >> 4) * 16) ^ ((lane & 7) << 4);
    csw[1] = 64 ^ csw[0];

    f32x4 acc[8][4];
    const f32x4 z = {0.f, 0.f, 0.f, 0.f};
#pragma unroll
    for (int i = 0; i < 8; ++i)
#pragma unroll
        for (int j = 0; j < 4; ++j) acc[i][j] = z;

#define KOFFS(KS, AK, BK)                                      \
    {  const int cb_ = (KS) & 3, khw_ = (KS) >> 2;             \
       const int kh_ = khw_ / 9, kw_ = khw_ - kh_ * 9;         \
       AK = (kh_ * 64 + kw_) * 256 + cb_ * 64;                 \
       BK = khw_ * 65536 + cb_ * 64; }

#define STAGE_A_HALF(H, AK, NB) do {                                               \
    GLD_LDS16(Xt + aoff[2*(H)]   + (AK), ldsA + (NB)*32768 + ((2*(H))*8   + wave)*1024); \
    GLD_LDS16(Xt + aoff[2*(H)+1] + (AK), ldsA + (NB)*32768 + ((2*(H)+1)*8 + wave)*1024); } while(0)
#define STAGE_B_HALF(H, BK, NB) do {                                               \
    GLD_LDS16(Wt + boff[2*(H)]   + (BK), ldsB + (NB)*32768 + ((2*(H))*8   + wave)*1024); \
    GLD_LDS16(Wt + boff[2*(H)+1] + (BK), ldsB + (NB)*32768 + ((2*(H)+1)*8 + wave)*1024); } while(0)

#define MFMA_PAIR(MI, NI, A, Bf)                                                        \
    acc[MI][NI] = __builtin_amdgcn_mfma_f32_16x16x32_f16((A)[0], (Bf)[0], acc[MI][NI], 0,0,0); \
    acc[MI][NI] = __builtin_amdgcn_mfma_f32_16x16x32_f16((A)[1], (Bf)[1], acc[MI][NI], 0,0,0);
#define MFMA_Q(MH, NH, BF)                                          \
    MFMA_PAIR((MH)*4+0, (NH)*2+0, af[0], BF[0]) MFMA_PAIR((MH)*4+0, (NH)*2+1, af[0], BF[1]) \
    MFMA_PAIR((MH)*4+1, (NH)*2+0, af[1], BF[0]) MFMA_PAIR((MH)*4+1, (NH)*2+1, af[1], BF[1]) \
    MFMA_PAIR((MH)*4+2, (NH)*2+0, af[2], BF[0]) MFMA_PAIR((MH)*4+2, (NH)*2+1, af[2], BF[1]) \
    MFMA_PAIR((MH)*4+3, (NH)*2+0, af[3], BF[0]) MFMA_PAIR((MH)*4+3, (NH)*2+1, af[3], BF[1])

    f16x8 af[4][2], bf0[2][2], bf1[2][2];

    // ---- prologue: stage tile 0 fully (order A0,B0,A1,B1) ----
    {
        int ak0, bk0;
        KOFFS(ksb, ak0, bk0);
        STAGE_A_HALF(0, ak0, 0);
        STAGE_B_HALF(0, bk0, 0);
        STAGE_A_HALF(1, ak0, 0);
        STAGE_B_HALF(1, bk0, 0);
    }
    WAITVM4();   // A0(0), B0(0) resident
    SBAR();

#pragma unroll 1
    for (int tt = 0; tt < NT; ++tt) {
        const int c = tt & 1, nc = c ^ 1;
        const int ksn = ksb + ((tt + 1 < NT) ? tt + 1 : tt);  // clamp (dup-stage tail)
        int akn, bkn;
        KOFFS(ksn, akn, bkn);
        const char* pA = ldsA + c * 32768;
        const char* pB = ldsB + c * 32768;

        // ---- P1: stage A-h0(t+1); read A0,B0; Q(0,0) ----
        STAGE_A_HALF(0, akn, nc);
#pragma unroll
        for (int k = 0; k < 4; ++k) {
            af[k][0] = *(const f16x8*)(pA + rowA[k] + csw[0]);
            af[k][1] = *(const f16x8*)(pA + rowA[k] + csw[1]);
        }
#pragma unroll
        for (int k = 0; k < 2; ++k) {
            bf0[k][0] = *(const f16x8*)(pB + rowB[k] + csw[0]);
            bf0[k][1] = *(const f16x8*)(pB + rowB[k] + csw[1]);
        }
        SBAR();
        __builtin_amdgcn_s_setprio(1);
        MFMA_Q(0, 0, bf0)
        __builtin_amdgcn_s_setprio(0);
        WAITVM2();   // A1(t), B1(t) resident (for all waves after next barrier)
        SBAR();

        // ---- P2: stage B-h0(t+1); read B1; Q(0,1) ----
        STAGE_B_HALF(0, bkn, nc);
#pragma unroll
        for (int k = 0; k < 2; ++k) {
            bf1[k][0] = *(const f16x8*)(pB + rowB[2 + k] + csw[0]);
            bf1[k][1] = *(const f16x8*)(pB + rowB[2 + k] + csw[1]);
        }
        SBAR();
        __builtin_amdgcn_s_setprio(1);
        MFMA_Q(0, 1, bf1)
        __builtin_amdgcn_s_setprio(0);
        SBAR();

        // ---- P3: stage A-h1(t+1); read A1; Q(1,1) ----
        STAGE_A_HALF(1, akn, nc);
#pragma unroll
        for (int k = 0; k < 4; ++k) {
            af[k][0] = *(const f16x8*)(pA + rowA[4 + k] + csw[0]);
            af[k][1] = *(const f16x8*)(pA + rowA[4 + k] + csw[1]);
        }
        SBAR();
        __builtin_amdgcn_s_setprio(1);
        MFMA_Q(1, 1, bf1)
        __builtin_amdgcn_s_setprio(0);
        SBAR();

        // ---- P4: stage B-h1(t+1); Q(1,0) ----
        STAGE_B_HALF(1, bkn, nc);
        SBAR();
        __builtin_amdgcn_s_setprio(1);
        MFMA_Q(1, 0, bf0)
        __builtin_amdgcn_s_setprio(0);
        WAITVM4();   // A0(t+1), B0(t+1) resident
        SBAR();
    }

    // ---- epilogue ----
    float* base = part + (long)sk * (M_TOTAL * 256);
    const int lrow = (lane >> 4) * 4;
#pragma unroll
    for (int nf = 0; nf < 4; ++nf) {
        const int n = wn * 64 + nf * 16 + (lane & 15);
#pragma unroll
        for (int mf = 0; mf < 8; ++mf) {
            const long mrow = m0 + wm * 128 + mf * 16 + lrow;
            float* cw = base + mrow * 256 + n;
#pragma unroll
            for (int j = 0; j < 4; ++j) cw[(long)j * 256] = acc[mf][nf][j];
        }
    }
}

// ---------------------------------------------------------------------------
// Kernel 4: partial-sum + bias + squash + 3-iter routing + acts.
// ---------------------------------------------------------------------------
__global__ __launch_bounds__(256) void routing_kernel(const float* __restrict__ part,
                                                      const float* __restrict__ bias,
                                                      const float* __restrict__ rb,
                                                      float* __restrict__ out, int nsplit)
{
    const int t   = threadIdx.x;
    const int m   = blockIdx.x * 8 + (t >> 5);
    const int cap = t & 31;
    const int b   = m / 784;
    const int rem = m - b * 784;
    const int oh  = rem / 28;
    const int ow  = rem - oh * 28;

    const float4 b0 = ((const float4*)(bias + cap * 8))[0];
    const float4 b1 = ((const float4*)(bias + cap * 8))[1];
    float v[8] = {b0.x, b0.y, b0.z, b0.w, b1.x, b1.y, b1.z, b1.w};
#pragma unroll 1
    for (int sk = 0; sk < nsplit; ++sk) {
        const float4* cp = (const float4*)(part + (long)sk * (M_TOTAL * 256) + (long)m * 256 + cap * 8);
        const float4 u0 = cp[0], u1 = cp[1];
        v[0] += u0.x; v[1] += u0.y; v[2] += u0.z; v[3] += u0.w;
        v[4] += u1.x; v[5] += u1.y; v[6] += u1.z; v[7] += u1.w;
    }

    float n2 = 0.f;
#pragma unroll
    for (int j = 0; j < 8; ++j) n2 += v[j] * v[j];
    const float f = (n2 / (1.f + n2)) / sqrtf(n2 + 1e-8f);
    float votes[8];
#pragma unroll
    for (int j = 0; j < 8; ++j) votes[j] = f * v[j];

    const float4* rp = (const float4*)(rb + ((long)(cap * 28 + oh) * 28 + ow) * 8);
    const float4 r0 = rp[0], r1 = rp[1];
    const float rbv[8] = {r0.x, r0.y, r0.z, r0.w, r1.x, r1.y, r1.z, r1.w};

    float logit = 0.f;
    float poses[8];
#pragma unroll 1
    for (int it = 0; it < 3; ++it) {
        float mx = logit;
#pragma unroll
        for (int d = 16; d > 0; d >>= 1) mx = fmaxf(mx, __shfl_xor(mx, d, 32));
        const float e = __expf(logit - mx);
        float se = e;
#pragma unroll
        for (int d = 16; d > 0; d >>= 1) se += __shfl_xor(se, d, 32);
        const float c = e / se;

        float s[8];
        float sn2 = 0.f;
#pragma unroll
        for (int j = 0; j < 8; ++j) { s[j] = c * votes[j] + rbv[j]; sn2 += s[j] * s[j]; }
        const float sf = (sn2 / (1.f + sn2)) / sqrtf(sn2 + 1e-8f);
        float dot = 0.f;
#pragma unroll
        for (int j = 0; j < 8; ++j) { poses[j] = sf * s[j]; dot += votes[j] * poses[j]; }
        logit += dot;
    }

    float pn2 = 0.f;
#pragma unroll
    for (int j = 0; j < 8; ++j) pn2 += poses[j] * poses[j];
    const float act = sqrtf(pn2);

    float* po = out + (((long)(b * 32 + cap) * 28 + oh) * 28 + ow) * 8;
    float4 o0 = {poses[0], poses[1], poses[2], poses[3]};
    float4 o1 = {poses[4], poses[5], poses[6], poses[7]};
    ((float4*)po)[0] = o0;
    ((float4*)po)[1] = o1;
    out[POSE_ELEMS + ((long)(b * 32 + cap) * 28 + oh) * 28 + ow] = act;
}

// ---------------------------------------------------------------------------
extern "C" void kernel_launch(void* const* d_in, const int* in_sizes, int n_in,
                              void* d_out, int out_size, void* d_ws, size_t ws_size,
                              hipStream_t stream)
{
    const float* x      = (const float*)d_in[0];
    const float* conv_w = (const float*)d_in[1];
    const float* conv_b = (const float*)d_in[2];
    const float* rb     = (const float*)d_in[3];
    float* out          = (float*)d_out;

    char* ws = (char*)d_ws;
    f16*   Xt   = (f16*)ws;                                  // 67,108,864 B
    f16*   Wt   = (f16*)(ws + 67108864);                     // 10,616,832 B
    const size_t base = 67108864 + 10616832;
    float* part = (float*)(ws + base);
    const size_t part_bytes = (size_t)M_TOTAL * 256 * 4;     // 25,690,112 B

    // split-K factor (must divide 324); limited by workspace (deterministic)
    int nsplit = 1;
    if      (ws_size >= base + 9 * part_bytes) nsplit = 9;
    else if (ws_size >= base + 6 * part_bytes) nsplit = 6;
    else if (ws_size >= base + 4 * part_bytes) nsplit = 4;
    else if (ws_size >= base + 2 * part_bytes) nsplit = 2;
    const int NT = 324 / nsplit;

    xt_kernel<<<dim3(4, 64, 32), 256, 0, stream>>>(x, Xt);
    wt_kernel<<<dim3(1024), 256, 0, stream>>>(conv_w, Wt);
    gemm_kernel<<<dim3(98 * nsplit), dim3(512), 0, stream>>>(Xt, Wt, part, nsplit, NT);
    routing_kernel<<<dim3(3136), 256, 0, stream>>>(part, conv_b, rb, out, nsplit);
}